// Round 1
// baseline (12326.452 us; speedup 1.0000x reference)
//
#include <hip/hip_runtime.h>
#include <cstdint>
#include <cstddef>

#define B_  32
#define T_  2048
#define D_  512
#define H_  512
#define NWG 32   // recurrent workgroups; each owns 16 h-cols = 64 gate-cols

typedef unsigned int   u32;
typedef unsigned short u16;
typedef u32   u32x4  __attribute__((ext_vector_type(4)));
typedef u32   u32x2  __attribute__((ext_vector_type(2)));
typedef float f32x4  __attribute__((ext_vector_type(4)));
typedef __bf16 bf16x8 __attribute__((ext_vector_type(8)));

__device__ __forceinline__ u16 f2bf(float f) {
  u32 u = __builtin_bit_cast(u32, f);
  u32 r = (u + 0x7fffu + ((u >> 16) & 1u)) >> 16;   // RNE
  return (u16)r;
}
__device__ __forceinline__ float bf2f(u16 h) {
  return __builtin_bit_cast(float, ((u32)h) << 16);
}
__device__ __forceinline__ f32x4 g4_from_bf(u32x2 p) {
  f32x4 r;
  r[0] = __builtin_bit_cast(float, (p[0] & 0xffffu) << 16);
  r[1] = __builtin_bit_cast(float, (p[0] & 0xffff0000u));
  r[2] = __builtin_bit_cast(float, (p[1] & 0xffffu) << 16);
  r[3] = __builtin_bit_cast(float, (p[1] & 0xffff0000u));
  return r;
}
__device__ __forceinline__ float sigm(float x) { return 1.0f / (1.0f + __expf(-x)); }

// ---------------------------------------------------------------------------
// K1: cast x [B][T][D] fp32 -> xb bf16, time-major rows m = t*32 + b
// ---------------------------------------------------------------------------
__global__ __launch_bounds__(256) void k_cast_x(const float* __restrict__ x,
                                                u16* __restrict__ xb) {
  long i = (long)blockIdx.x * 256 + threadIdx.x;   // 4,194,304 total
  int  dc = (int)(i & 63);                          // 8-elem chunk in d
  long m  = i >> 6;                                 // 0..65535
  int  t  = (int)(m >> 5), b = (int)(m & 31);
  const float* src = x + ((long)b * T_ + t) * D_ + (dc << 3);
  f32x4 a = *(const f32x4*)(src);
  f32x4 c = *(const f32x4*)(src + 4);
  u32x4 pv;
  pv[0] = (u32)f2bf(a[0]) | ((u32)f2bf(a[1]) << 16);
  pv[1] = (u32)f2bf(a[2]) | ((u32)f2bf(a[3]) << 16);
  pv[2] = (u32)f2bf(c[0]) | ((u32)f2bf(c[1]) << 16);
  pv[3] = (u32)f2bf(c[2]) | ((u32)f2bf(c[3]) << 16);
  *(u32x4*)(xb + (m << 9) + (dc << 3)) = pv;
}

// ---------------------------------------------------------------------------
// K2: pack weights transposed + gate-interleaved.
//   col n = hcol*4 + gate   (gate: 0=i,1=f,2=o,3=c)
//   w4xt[n][k] = Wx{gate}[k][hcol]   (bf16, [2048][512])
//   w4ht[n][k] = Wh{gate}[k][hcol]
//   bias4[n]   = b{gate}[hcol]
// ---------------------------------------------------------------------------
__global__ __launch_bounds__(256) void k_pack_w(
    const float* __restrict__ Wxi, const float* __restrict__ Whi, const float* __restrict__ bi,
    const float* __restrict__ Wxf, const float* __restrict__ Whf, const float* __restrict__ bfv,
    const float* __restrict__ Wxo, const float* __restrict__ Who, const float* __restrict__ bo,
    const float* __restrict__ Wxc, const float* __restrict__ Whc, const float* __restrict__ bc,
    u16* __restrict__ w4xt, u16* __restrict__ w4ht, float* __restrict__ bias4) {
  int blk = blockIdx.x, tid = threadIdx.x;
  if (blk == 1024) {
    for (int i = tid; i < 2048; i += 256) {
      int hcol = i >> 2, g = i & 3;
      const float* bsrc = (g == 0 ? bi : g == 1 ? bfv : g == 2 ? bo : bc);
      bias4[i] = bsrc[hcol];
    }
    return;
  }
  bool isx = (blk < 512);
  long s = (long)(isx ? blk : blk - 512) * 256 + tid;  // chunk id 0..131071
  int n = (int)(s >> 6);
  int c = (int)(s & 63);
  int hcol = n >> 2, g = n & 3;
  const float* W = isx ? (g == 0 ? Wxi : g == 1 ? Wxf : g == 2 ? Wxo : Wxc)
                       : (g == 0 ? Whi : g == 1 ? Whf : g == 2 ? Who : Whc);
  u16* dst = (isx ? w4xt : w4ht) + ((long)n << 9) + (c << 3);
#pragma unroll
  for (int j = 0; j < 8; j++) dst[j] = f2bf(W[(long)((c << 3) + j) * H_ + hcol]);
}

// ---------------------------------------------------------------------------
// K3: GEMM gates0[m][n] = sum_k xb[m][k]*w4xt[n][k] + bias4[n]
//   128x128 tile, BK=32, 4 waves, reg-staged LDS, mfma_f32_16x16x32_bf16
// ---------------------------------------------------------------------------
template <int G32>
__global__ __launch_bounds__(256) void k_gemm(const u16* __restrict__ xb,
                                              const u16* __restrict__ w4xt,
                                              const float* __restrict__ bias4,
                                              char* __restrict__ gates0) {
  __shared__ __align__(16) unsigned char As[128 * 32 * 2];
  __shared__ __align__(16) unsigned char Bs[128 * 32 * 2];
  int tid = threadIdx.x;
  int bm = blockIdx.x & 511;
  int bn = blockIdx.x >> 9;
  long m0 = (long)bm << 7;
  int  n0 = bn << 7;
  int wv = tid >> 6, lane = tid & 63;
  int wr = wv >> 1, wc = wv & 1;
  int lr = lane & 15, lc = lane >> 4;

  f32x4 acc[4][4];
#pragma unroll
  for (int i = 0; i < 4; i++)
#pragma unroll
    for (int j = 0; j < 4; j++) acc[i][j] = (f32x4){0.f, 0.f, 0.f, 0.f};

  for (int kt = 0; kt < 16; kt++) {
#pragma unroll
    for (int h = 0; h < 2; h++) {
      int s = h * 256 + tid;
      int row = s >> 2, ch = s & 3;
      u32x4 va = *(const u32x4*)(xb + ((m0 + row) << 9) + (kt << 5) + (ch << 3));
      *(u32x4*)(As + (((row << 6) + (ch << 4)) ^ ((row & 3) << 4))) = va;
      u32x4 vb = *(const u32x4*)(w4xt + (((long)n0 + row) << 9) + (kt << 5) + (ch << 3));
      *(u32x4*)(Bs + (((row << 6) + (ch << 4)) ^ ((row & 3) << 4))) = vb;
    }
    __syncthreads();
    bf16x8 af[4], bfr[4];
#pragma unroll
    for (int mi = 0; mi < 4; mi++) {
      int row = (wr << 6) + (mi << 4) + lr;
      af[mi] = __builtin_bit_cast(bf16x8,
          *(const u32x4*)(As + (((row << 6) + (lc << 4)) ^ ((row & 3) << 4))));
    }
#pragma unroll
    for (int ni = 0; ni < 4; ni++) {
      int row = (wc << 6) + (ni << 4) + lr;
      bfr[ni] = __builtin_bit_cast(bf16x8,
          *(const u32x4*)(Bs + (((row << 6) + (lc << 4)) ^ ((row & 3) << 4))));
    }
#pragma unroll
    for (int mi = 0; mi < 4; mi++)
#pragma unroll
      for (int ni = 0; ni < 4; ni++)
        acc[mi][ni] = __builtin_amdgcn_mfma_f32_16x16x32_bf16(af[mi], bfr[ni], acc[mi][ni], 0, 0, 0);
    __syncthreads();
  }
  // epilogue: D row = 4*lc + r, col = lr (m89-verified layout)
#pragma unroll
  for (int mi = 0; mi < 4; mi++) {
#pragma unroll
    for (int ni = 0; ni < 4; ni++) {
      int col = n0 + (wc << 6) + (ni << 4) + lr;
      float bias = bias4[col];
#pragma unroll
      for (int r = 0; r < 4; r++) {
        long row = m0 + (wr << 6) + (mi << 4) + (lc << 2) + r;
        float v = acc[mi][ni][r] + bias;
        if constexpr (G32) ((float*)gates0)[(row << 11) + col] = v;
        else               ((u16*)gates0)[(row << 11) + col] = f2bf(v);
      }
    }
  }
}

// ---------------------------------------------------------------------------
// K4: persistent recurrent kernel. 32 WGs x 256 threads, one agent-scope
// barrier per timestep, Wh slice LDS-resident, double-buffered h (bf16).
// ---------------------------------------------------------------------------
template <int G32>
__global__ __launch_bounds__(256) void k_rnn(const u16* __restrict__ w4ht,
                                             const char* __restrict__ gates0,
                                             const float* __restrict__ wd,
                                             u16* __restrict__ h_buf,   // [2][32][512]
                                             float* __restrict__ po,    // [T][NWG][32]
                                             unsigned* __restrict__ bar) {
  __shared__ __align__(16) unsigned char whs[64 * 512 * 2];   // 64 KB
  __shared__ __align__(16) unsigned char hlds[32 * 512 * 2];  // 32 KB
  __shared__ __align__(16) float G_all[32 * 64];              // 8 KB
  __shared__ float c_s[32 * 16];
  __shared__ float hn_s[32 * 16];
  __shared__ float wd_s[16];

  const int tid = threadIdx.x;
  const int w = blockIdx.x;
  const int wv = tid >> 6, lane = tid & 63;
  const int lr = lane & 15, lc = lane >> 4;

  // load Wh slice to LDS (XOR-swizzled, G4: break 16-way row-stride conflicts)
#pragma unroll 4
  for (int i = 0; i < 16; i++) {
    int s = i * 256 + tid;
    int n = s >> 6, c = s & 63;
    u32x4 v = *(const u32x4*)(w4ht + ((long)((w << 6) + n) << 9) + (c << 3));
    *(u32x4*)(whs + (((n << 10) + (c << 4)) ^ ((n & 7) << 4))) = v;
  }
  for (int i = tid; i < 512; i += 256) c_s[i] = 0.0f;
  if (tid < 16) wd_s[tid] = wd[(w << 4) + tid];
  __syncthreads();

  const int pb = tid >> 4;   // 0..15
  const int jj = tid & 15;   // 0..15
  const u32 swA = (u32)((lr & 7) << 4);
  const int nrow = (wv << 4) + lr;
  const u32 bbase = (u32)(nrow << 10);
  const u32 swB = (u32)((nrow & 7) << 4);
  const u32 a0base = (u32)(lr << 10);
  const u32 a1base = (u32)((16 + lr) << 10);

#pragma unroll 1
  for (int t = 0; t < T_; t++) {
    const u16* hb_cur = h_buf + ((t & 1) << 14);
    u16* hb_nxt = h_buf + (((t + 1) & 1) << 14);

    // phase A: issue this step's gates0 loads (independent of h; hides latency)
    f32x4 gfa, gfb; u32x2 gba, gbb;
    {
      long i0 = ((long)t * 32 + pb) * 2048 + (w << 6) + (jj << 2);
      long i1 = ((long)t * 32 + pb + 16) * 2048 + (w << 6) + (jj << 2);
      if constexpr (G32) {
        gfa = *(const f32x4*)((const float*)gates0 + i0);
        gfb = *(const f32x4*)((const float*)gates0 + i1);
      } else {
        gba = *(const u32x2*)((const u16*)gates0 + i0);
        gbb = *(const u32x2*)((const u16*)gates0 + i1);
      }
    }

    // phase B: stage h_t -> LDS (swizzled)
    u32x4 hv[8];
#pragma unroll
    for (int i = 0; i < 8; i++) {
      int s = i * 256 + tid;
      hv[i] = *(const u32x4*)(hb_cur + ((s >> 6) << 9) + ((s & 63) << 3));
    }
#pragma unroll
    for (int i = 0; i < 8; i++) {
      int s = i * 256 + tid;
      int b = s >> 6, c = s & 63;
      *(u32x4*)(hlds + (((b << 10) + (c << 4)) ^ ((b & 7) << 4))) = hv[i];
    }
    __syncthreads();

    // phase C: G = h @ Wh_slice   (A rows = batch, B rows = gate-col)
    f32x4 acc0 = {0.f, 0.f, 0.f, 0.f}, acc1 = {0.f, 0.f, 0.f, 0.f};
#pragma unroll
    for (int kk = 0; kk < 16; kk++) {
      u32 ko = (u32)((kk << 6) + (lc << 4));
      bf16x8 bfr = __builtin_bit_cast(bf16x8, *(const u32x4*)(whs + ((bbase + ko) ^ swB)));
      bf16x8 a0  = __builtin_bit_cast(bf16x8, *(const u32x4*)(hlds + ((a0base + ko) ^ swA)));
      bf16x8 a1  = __builtin_bit_cast(bf16x8, *(const u32x4*)(hlds + ((a1base + ko) ^ swA)));
      acc0 = __builtin_amdgcn_mfma_f32_16x16x32_bf16(a0, bfr, acc0, 0, 0, 0);
      acc1 = __builtin_amdgcn_mfma_f32_16x16x32_bf16(a1, bfr, acc1, 0, 0, 0);
    }
#pragma unroll
    for (int r = 0; r < 4; r++) {
      G_all[(((lc << 2) + r) << 6) + (wv << 4) + lr]        = acc0[r];
      G_all[(((lc << 2) + r + 16) << 6) + (wv << 4) + lr]   = acc1[r];
    }
    __syncthreads();

    // phase D: pointwise LSTM cell for (pb, jj) and (pb+16, jj)
    {
      f32x4 g0a, g0b;
      if constexpr (G32) { g0a = gfa; g0b = gfb; }
      else { g0a = g4_from_bf(gba); g0b = g4_from_bf(gbb); }

      f32x4 gv = *(const f32x4*)(&G_all[(pb << 6) + (jj << 2)]);
      float I = sigm(gv[0] + g0a[0]);
      float F = sigm(gv[1] + g0a[1]);
      float O = sigm(gv[2] + g0a[2]);
      float Ct = tanhf(gv[3] + g0a[3]);
      float c0 = c_s[(pb << 4) + jj];
      float cn = F * c0 + I * Ct;
      float hn = O * tanhf(cn);
      c_s[(pb << 4) + jj] = cn;
      hn_s[(pb << 4) + jj] = hn;
      hb_nxt[(pb << 9) + (w << 4) + jj] = f2bf(hn);

      f32x4 gw = *(const f32x4*)(&G_all[((pb + 16) << 6) + (jj << 2)]);
      float I2 = sigm(gw[0] + g0b[0]);
      float F2 = sigm(gw[1] + g0b[1]);
      float O2 = sigm(gw[2] + g0b[2]);
      float Ct2 = tanhf(gw[3] + g0b[3]);
      float c02 = c_s[((pb + 16) << 4) + jj];
      float cn2 = F2 * c02 + I2 * Ct2;
      float hn2 = O2 * tanhf(cn2);
      c_s[((pb + 16) << 4) + jj] = cn2;
      hn_s[((pb + 16) << 4) + jj] = hn2;
      hb_nxt[((pb + 16) << 9) + (w << 4) + jj] = f2bf(hn2);
    }
    __syncthreads();

    // phase E: per-WG partial of hs@Wd
    if (tid < 32) {
      float s = 0.f;
#pragma unroll
      for (int j = 0; j < 16; j++) s += hn_s[(tid << 4) + j] * wd_s[j];
      po[((long)t * NWG + w) * 32 + tid] = s;
    }

    // phase F: grid barrier (monotonic epoch; release publishes hb_nxt)
    if (tid == 0) {
      unsigned old = __hip_atomic_fetch_add(&bar[0], 1u, __ATOMIC_RELEASE, __HIP_MEMORY_SCOPE_AGENT);
      if (old == (unsigned)(t + 1) * NWG - 1u) {
        __hip_atomic_store(&bar[1], (unsigned)(t + 1), __ATOMIC_RELEASE, __HIP_MEMORY_SCOPE_AGENT);
      } else {
        while (__hip_atomic_load(&bar[1], __ATOMIC_RELAXED, __HIP_MEMORY_SCOPE_AGENT) <
               (unsigned)(t + 1)) {
          __builtin_amdgcn_s_sleep(1);
        }
      }
    }
    __syncthreads();
    {
      unsigned d = __hip_atomic_load(&bar[1], __ATOMIC_ACQUIRE, __HIP_MEMORY_SCOPE_AGENT);
      asm volatile("" ::"v"(d) : "memory");   // keep acquire, fence later loads
    }
  }
}

// ---------------------------------------------------------------------------
// K5: out[b,t] = sum_w po[t][w][b] + bd
// ---------------------------------------------------------------------------
__global__ __launch_bounds__(256) void k_reduce(const float* __restrict__ po,
                                                const float* __restrict__ bd,
                                                float* __restrict__ out) {
  int tid = threadIdx.x;
  int b = tid & 31, tl = tid >> 5;
  int t = blockIdx.x * 8 + tl;
  float s = bd[0];
#pragma unroll
  for (int w = 0; w < NWG; w++) s += po[((long)t * NWG + w) * 32 + b];
  out[(long)b * T_ + t] = s;
}

// ---------------------------------------------------------------------------
extern "C" void kernel_launch(void* const* d_in, const int* in_sizes, int n_in,
                              void* d_out, int out_size, void* d_ws, size_t ws_size,
                              hipStream_t stream) {
  const float* x   = (const float*)d_in[0];
  const float* Wxi = (const float*)d_in[1];
  const float* Whi = (const float*)d_in[2];
  const float* bi  = (const float*)d_in[3];
  const float* Wxf = (const float*)d_in[4];
  const float* Whf = (const float*)d_in[5];
  const float* bfv = (const float*)d_in[6];
  const float* Wxo = (const float*)d_in[7];
  const float* Who = (const float*)d_in[8];
  const float* bo  = (const float*)d_in[9];
  const float* Wxc = (const float*)d_in[10];
  const float* Whc = (const float*)d_in[11];
  const float* bc  = (const float*)d_in[12];
  const float* Wd  = (const float*)d_in[13];
  const float* bd  = (const float*)d_in[14];

  char* ws = (char*)d_ws;
  constexpr size_t OFF_BAR  = 0;
  constexpr size_t OFF_HBUF = 256;                         // 2*32*512*2 = 65536
  constexpr size_t OFF_PO   = 65792;                       // 2048*32*32*4 = 8 MB
  constexpr size_t OFF_XB   = OFF_PO + 8388608;            // 64 MB bf16
  constexpr size_t OFF_W4XT = OFF_XB + 67108864;           // 2 MB
  constexpr size_t OFF_W4HT = OFF_W4XT + 2097152;          // 2 MB
  constexpr size_t OFF_BIAS = OFF_W4HT + 2097152;          // 8 KB
  constexpr size_t OFF_G0   = OFF_BIAS + 8192;
  constexpr size_t TOT_F32  = OFF_G0 + (size_t)65536 * 2048 * 4;  // ~588 MB
  bool g32 = (ws_size >= TOT_F32);

  unsigned* bar  = (unsigned*)(ws + OFF_BAR);
  u16* h_buf     = (u16*)(ws + OFF_HBUF);
  float* po      = (float*)(ws + OFF_PO);
  u16* xb        = (u16*)(ws + OFF_XB);
  u16* w4xt      = (u16*)(ws + OFF_W4XT);
  u16* w4ht      = (u16*)(ws + OFF_W4HT);
  float* bias4   = (float*)(ws + OFF_BIAS);
  char* gates0   = ws + OFF_G0;

  hipMemsetAsync(d_ws, 0, OFF_HBUF + 65536, stream);  // barrier + h_buf zeros

  k_cast_x<<<16384, 256, 0, stream>>>(x, xb);
  k_pack_w<<<1025, 256, 0, stream>>>(Wxi, Whi, bi, Wxf, Whf, bfv, Wxo, Who, bo,
                                     Wxc, Whc, bc, w4xt, w4ht, bias4);
  if (g32) {
    k_gemm<1><<<8192, 256, 0, stream>>>(xb, w4xt, bias4, gates0);
    k_rnn<1><<<NWG, 256, 0, stream>>>(w4ht, gates0, Wd, h_buf, po, bar);
  } else {
    k_gemm<0><<<8192, 256, 0, stream>>>(xb, w4xt, bias4, gates0);
    k_rnn<0><<<NWG, 256, 0, stream>>>(w4ht, gates0, Wd, h_buf, po, bar);
  }
  k_reduce<<<256, 256, 0, stream>>>(po, bd, (float*)d_out);
}